// Round 1
// baseline (1114.465 us; speedup 1.0000x reference)
//
#include <hip/hip_runtime.h>
#include <hip/hip_bf16.h>

#define N_NODES 100000
#define N_EDGES 1600000
#define NODE_DIM 128
#define MEM 64
#define NEG_SLOPE 0.2f

__device__ __forceinline__ unsigned enc_f(float f) {
    unsigned u = __float_as_uint(f);
    return (u & 0x80000000u) ? ~u : (u | 0x80000000u);
}
__device__ __forceinline__ float dec_f(unsigned u) {
    u = (u & 0x80000000u) ? (u & 0x7FFFFFFFu) : ~u;
    return __uint_as_float(u);
}
__device__ __forceinline__ float lrelu(float v) {
    return v >= 0.f ? v : NEG_SLOPE * v;
}

// Kernel A: per node -- projected = state@w_in.T + b_in; mem_enh = proj+goal+mem;
// xt = mem_enh@w_gat.T; a_s = xt.att_src; a_d = xt.att_dst; m_enc = enc(leaky(a_s+a_d)) (self loop)
__global__ __launch_bounds__(256) void kA(
    const float* __restrict__ state, const float* __restrict__ goal,
    const float* __restrict__ mem, const float* __restrict__ w_in,
    const float* __restrict__ b_in, const float* __restrict__ w_gat,
    const float* __restrict__ att_src, const float* __restrict__ att_dst,
    float* __restrict__ me_out, float* __restrict__ xt_out,
    float* __restrict__ as_out, float* __restrict__ ad_out,
    unsigned* __restrict__ m_enc)
{
    __shared__ float s_win[64 * 129];
    __shared__ float s_wgat[64 * 65];
    __shared__ float s_state[4][128];
    __shared__ float s_me[4][64];
    const int tid = threadIdx.x;
    for (int i = tid; i < 64 * 128; i += 256) {
        int r = i >> 7, c = i & 127;
        s_win[r * 129 + c] = w_in[i];
    }
    for (int i = tid; i < 64 * 64; i += 256) {
        int r = i >> 6, c = i & 63;
        s_wgat[r * 65 + c] = w_gat[i];
    }
    __syncthreads();
    const int wave = tid >> 6, lane = tid & 63;
    const float bin = b_in[lane];
    const float asrc = att_src[lane], adst = att_dst[lane];
    const int n_pad = (N_NODES + 3) & ~3;
    for (int base = blockIdx.x * 4; base < n_pad; base += gridDim.x * 4) {
        const int node = base + wave;
        const bool act = node < N_NODES;
        if (act) {
            const float* sp = state + (long)node * NODE_DIM;
            s_state[wave][lane] = sp[lane];
            s_state[wave][lane + 64] = sp[lane + 64];
        }
        __syncthreads();
        float me = 0.f;
        if (act) {
            float acc = bin;
            const float* wr = s_win + lane * 129;
            #pragma unroll
            for (int k = 0; k < 128; ++k) acc += s_state[wave][k] * wr[k];
            const long off = (long)node * MEM + lane;
            me = acc + goal[off] + mem[off];
            s_me[wave][lane] = me;
        }
        __syncthreads();
        if (act) {
            float acc = 0.f;
            const float* wr = s_wgat + lane * 65;
            #pragma unroll
            for (int k = 0; k < 64; ++k) acc += s_me[wave][k] * wr[k];
            const long off = (long)node * MEM + lane;
            xt_out[off] = acc;
            me_out[off] = me;
            float ps = acc * asrc, pd = acc * adst;
            #pragma unroll
            for (int o = 32; o; o >>= 1) {
                ps += __shfl_xor(ps, o);
                pd += __shfl_xor(pd, o);
            }
            if (lane == 0) {
                as_out[node] = ps;
                ad_out[node] = pd;
                m_enc[node] = enc_f(lrelu(ps + pd));
            }
        }
        __syncthreads();
    }
}

// Kernel B: edge max scatter
__global__ __launch_bounds__(256) void kB(
    const int* __restrict__ src, const int* __restrict__ dst,
    const float* __restrict__ as_, const float* __restrict__ ad_,
    unsigned* __restrict__ m_enc)
{
    const int e = blockIdx.x * 256 + threadIdx.x;
    if (e >= N_EDGES) return;
    const int s = src[e], d = dst[e];
    atomicMax(m_enc + d, enc_f(lrelu(as_[s] + ad_[d])));
}

// Kernel C: decode max, init denom and ctx numerator with self-loop term
__global__ __launch_bounds__(256) void kC(
    const float* __restrict__ xt, const float* __restrict__ as_,
    const float* __restrict__ ad_, const unsigned* __restrict__ m_enc,
    float* __restrict__ mf, float* __restrict__ denom, float* __restrict__ ctxnum)
{
    const long i = (long)blockIdx.x * 256 + threadIdx.x;
    if (i >= (long)N_NODES * MEM) return;
    const int node = (int)(i >> 6), d = (int)(i & 63);
    const float m = dec_f(m_enc[node]);
    const float es = lrelu(as_[node] + ad_[node]);
    const float w = __expf(es - m);
    if (d == 0) { mf[node] = m; denom[node] = w; }
    ctxnum[i] = xt[i] * w;
}

// Kernel D: per (edge, dim) weighted scatter-add of numerators + denom
__global__ __launch_bounds__(256) void kD(
    const int* __restrict__ src, const int* __restrict__ dst,
    const float* __restrict__ as_, const float* __restrict__ ad_,
    const float* __restrict__ mf, const float* __restrict__ xt,
    float* __restrict__ denom, float* __restrict__ ctxnum)
{
    const long i = (long)blockIdx.x * 256 + threadIdx.x;
    if (i >= (long)N_EDGES * MEM) return;
    const int e = (int)(i >> 6), d = (int)(i & 63);
    const int s = src[e], dn = dst[e];
    const float w = __expf(lrelu(as_[s] + ad_[dn]) - mf[dn]);
    if (d == 0) atomicAdd(denom + dn, w);
    atomicAdd(ctxnum + (long)dn * MEM + d, xt[(long)s * MEM + d] * w);
}

// Kernel E: ctx = ctxnum/denom + b_gat; memory_input = mem_enh + ctx; GRU cell
__global__ __launch_bounds__(256) void kE(
    const float* __restrict__ me, const float* __restrict__ ctxnum,
    const float* __restrict__ denom, const float* __restrict__ b_gat,
    const float* __restrict__ h, const float* __restrict__ w_ih,
    const float* __restrict__ w_hh, const float* __restrict__ b_ih,
    const float* __restrict__ b_hh, float* __restrict__ out)
{
    __shared__ float s_wih[192 * 65];
    __shared__ float s_whh[192 * 65];
    __shared__ float s_x[4][64];
    __shared__ float s_h[4][64];
    const int tid = threadIdx.x;
    for (int i = tid; i < 192 * 64; i += 256) {
        int r = i >> 6, c = i & 63;
        s_wih[r * 65 + c] = w_ih[i];
        s_whh[r * 65 + c] = w_hh[i];
    }
    __syncthreads();
    const int wave = tid >> 6, lane = tid & 63;
    const float bg = b_gat[lane];
    const float bir = b_ih[lane], biz = b_ih[64 + lane], binn = b_ih[128 + lane];
    const float bhr = b_hh[lane], bhz = b_hh[64 + lane], bhn = b_hh[128 + lane];
    const int n_pad = (N_NODES + 3) & ~3;
    for (int base = blockIdx.x * 4; base < n_pad; base += gridDim.x * 4) {
        const int node = base + wave;
        const bool act = node < N_NODES;
        float hval = 0.f;
        if (act) {
            const long off = (long)node * MEM + lane;
            const float ctx = ctxnum[off] / denom[node] + bg;
            const float x = me[off] + ctx;
            hval = h[off];
            s_x[wave][lane] = x;
            s_h[wave][lane] = hval;
        }
        __syncthreads();
        if (act) {
            float ir = bir, iz = biz, inn = binn;
            float hr = bhr, hz = bhz, hn = bhn;
            const float* wi0 = s_wih + lane * 65;
            const float* wi1 = s_wih + (64 + lane) * 65;
            const float* wi2 = s_wih + (128 + lane) * 65;
            const float* wh0 = s_whh + lane * 65;
            const float* wh1 = s_whh + (64 + lane) * 65;
            const float* wh2 = s_whh + (128 + lane) * 65;
            #pragma unroll
            for (int k = 0; k < 64; ++k) {
                const float xv = s_x[wave][k], hv = s_h[wave][k];
                ir += xv * wi0[k]; iz += xv * wi1[k]; inn += xv * wi2[k];
                hr += hv * wh0[k]; hz += hv * wh1[k]; hn += hv * wh2[k];
            }
            const float r = 1.f / (1.f + __expf(-(ir + hr)));
            const float z = 1.f / (1.f + __expf(-(iz + hz)));
            const float n = tanhf(inn + r * hn);
            out[(long)node * MEM + lane] = (1.f - z) * n + z * hval;
        }
        __syncthreads();
    }
}

extern "C" void kernel_launch(void* const* d_in, const int* in_sizes, int n_in,
                              void* d_out, int out_size, void* d_ws, size_t ws_size,
                              hipStream_t stream) {
    const float* state = (const float*)d_in[0];
    const float* goal  = (const float*)d_in[1];
    const float* mem   = (const float*)d_in[2];
    const int*   ei    = (const int*)d_in[3];
    const float* w_in  = (const float*)d_in[4];
    const float* b_in  = (const float*)d_in[5];
    const float* w_gat = (const float*)d_in[6];
    const float* att_s = (const float*)d_in[7];
    const float* att_d = (const float*)d_in[8];
    const float* b_gat = (const float*)d_in[9];
    const float* w_ih  = (const float*)d_in[10];
    const float* w_hh  = (const float*)d_in[11];
    const float* b_ih  = (const float*)d_in[12];
    const float* b_hh  = (const float*)d_in[13];
    float* out = (float*)d_out;

    const int* e_src = ei;
    const int* e_dst = ei + N_EDGES;

    // workspace layout (floats)
    float* ws = (float*)d_ws;
    float* me_buf  = ws;                            // N*64
    float* xt_buf  = me_buf + (long)N_NODES * MEM;  // N*64
    float* as_buf  = xt_buf + (long)N_NODES * MEM;  // N
    float* ad_buf  = as_buf + N_NODES;              // N
    unsigned* m_enc = (unsigned*)(ad_buf + N_NODES);// N
    float* mf_buf  = (float*)(m_enc + N_NODES);     // N
    float* dn_buf  = mf_buf + N_NODES;              // N
    float* cn_buf  = dn_buf + N_NODES;              // N*64

    hipLaunchKernelGGL(kA, dim3(2048), dim3(256), 0, stream,
        state, goal, mem, w_in, b_in, w_gat, att_s, att_d,
        me_buf, xt_buf, as_buf, ad_buf, m_enc);

    hipLaunchKernelGGL(kB, dim3((N_EDGES + 255) / 256), dim3(256), 0, stream,
        e_src, e_dst, as_buf, ad_buf, m_enc);

    hipLaunchKernelGGL(kC, dim3((N_NODES * MEM + 255) / 256), dim3(256), 0, stream,
        xt_buf, as_buf, ad_buf, m_enc, mf_buf, dn_buf, cn_buf);

    hipLaunchKernelGGL(kD, dim3((int)(((long)N_EDGES * MEM + 255) / 256)), dim3(256), 0, stream,
        e_src, e_dst, as_buf, ad_buf, mf_buf, xt_buf, dn_buf, cn_buf);

    hipLaunchKernelGGL(kE, dim3(1024), dim3(256), 0, stream,
        me_buf, cn_buf, dn_buf, b_gat, mem, w_ih, w_hh, b_ih, b_hh, out);
}